// Round 5
// baseline (185.485 us; speedup 1.0000x reference)
//
#include <hip/hip_runtime.h>
#include <hip/hip_bf16.h>

// B=64, N=64, P=128, K=16, M=N*N=4096, T=4096
// Outputs: Z [64,64] then w [64,128,4096], concatenated f32.
//
// Pipeline (2 kernels + 1 tiny memset):
//   k_gemm : part[tc][k][m] = sum_{t in 256-chunk} W[k][t]^2 * G[t][m]
//            last block per m-slice (atomic counter) sums the 16 partials in
//            fixed tc order -> wg = sum, E = exp(-wg)   (bit-deterministic)
//   k_wz   : blocks 0..8191    -> w[b,p,:] = wg[idx(b,p)][:]
//            blocks 8192..8447 -> Z[b][i] = sum_k E[k][i,:] . s[b,k,:]

// ---------------------------------------------------------------------------
__global__ __launch_bounds__(256) void k_gemm(const float* __restrict__ W,
                                              const float* __restrict__ G,
                                              float* __restrict__ part,
                                              float* __restrict__ wg,
                                              float* __restrict__ E,
                                              unsigned* __restrict__ cnt) {
    __shared__ float buf[8192];        // 32 KB: w2 [16][256] (16KB), then red (32KB)
    __shared__ unsigned old_s;
    const int tc  = blockIdx.x & 15;   // t-chunk (256 t each)
    const int mg  = blockIdx.x >> 4;   // m-slice (64 floats = 16 float4 each)
    const int tid = threadIdx.x;
    const int tt  = tid >> 4;          // 0..15 t-sublane
    const int col = tid & 15;          // 0..15 float4 within m-slice
    const int t0  = tc * 256;

    // stage W^2 for this t-chunk (coalesced per k)
#pragma unroll
    for (int k = 0; k < 16; ++k) {
        float v = W[k * 4096 + t0 + tid];
        buf[k * 256 + tid] = v * v;
    }
    __syncthreads();

    const float4* G4 = (const float4*)G;
    const int mq = mg * 16 + col;      // float4 column (0..1023)

    float4 acc[16];
#pragma unroll
    for (int k = 0; k < 16; ++k) acc[k] = make_float4(0.f, 0.f, 0.f, 0.f);

#pragma unroll 8
    for (int i = 0; i < 16; ++i) {
        const int tl = tt * 16 + i;
        const float4 g4 = G4[(size_t)(t0 + tl) * 1024 + mq];
#pragma unroll
        for (int k = 0; k < 16; ++k) {
            const float s = buf[k * 256 + tl];
            acc[k].x = fmaf(s, g4.x, acc[k].x);
            acc[k].y = fmaf(s, g4.y, acc[k].y);
            acc[k].z = fmaf(s, g4.z, acc[k].z);
            acc[k].w = fmaf(s, g4.w, acc[k].w);
        }
    }
    __syncthreads();                   // w2 dead; reuse buf as red staging

    // in-block reduction over tt: 2 rounds of 8 k, red aliases buf (32 KB)
    float4* red = (float4*)buf;
    float4* p4  = (float4*)part;
#pragma unroll
    for (int r = 0; r < 2; ++r) {
#pragma unroll
        for (int ks = 0; ks < 8; ++ks)
            red[ks * 256 + tid] = acc[r * 8 + ks];
        __syncthreads();
        if (tid < 128) {
            const int ks = tid >> 4;   // 0..7
            const int c2 = tid & 15;   // 0..15
            float4 s = make_float4(0.f, 0.f, 0.f, 0.f);
#pragma unroll
            for (int t2 = 0; t2 < 16; ++t2) {
                float4 v = red[ks * 256 + t2 * 16 + c2];
                s.x += v.x; s.y += v.y; s.z += v.z; s.w += v.w;
            }
            const int k = r * 8 + ks;
            p4[(size_t)tc * 16384 + (size_t)k * 1024 + mg * 16 + c2] = s;
        }
        __syncthreads();
    }

    // split-K fixup: 16th arriver for this mg sums partials (fixed tc order)
    __threadfence();                   // release partial writes (agent scope)
    if (tid == 0)
        old_s = __hip_atomic_fetch_add(&cnt[mg], 1u, __ATOMIC_ACQ_REL,
                                       __HIP_MEMORY_SCOPE_AGENT);
    __syncthreads();
    if (old_s == 15u) {
        __threadfence();               // acquire: invalidate stale cache lines
        const int k = tid >> 4;        // 0..15
        const int c = tid & 15;        // 0..15
        float4 s = make_float4(0.f, 0.f, 0.f, 0.f);
#pragma unroll
        for (int tc2 = 0; tc2 < 16; ++tc2) {
            float4 v = p4[(size_t)tc2 * 16384 + (size_t)k * 1024 + mg * 16 + c];
            s.x += v.x; s.y += v.y; s.z += v.z; s.w += v.w;
        }
        const size_t o = (size_t)k * 1024 + mg * 16 + c;
        ((float4*)wg)[o] = s;
        ((float4*)E)[o]  = make_float4(expf(-s.x), expf(-s.y),
                                       expf(-s.z), expf(-s.w));
    }
}

// ---------------------------------------------------------------------------
// blocks 0..8191: w gather.  blocks 8192..8447: Z (b = zb>>2, iq = zb&3).
__global__ __launch_bounds__(256) void k_wz(const float* __restrict__ x,
                                            const float* __restrict__ xmask,
                                            const float* __restrict__ wg,
                                            const float* __restrict__ E,
                                            float* __restrict__ wout,
                                            float* __restrict__ zout) {
    __shared__ float sw[4][16][64];   // 16 KB (z only)
    __shared__ int   idx[128];
    __shared__ float zr[16][16];
    const int tid = threadIdx.x;

    if (blockIdx.x < 8192) {
        const int bp = blockIdx.x;
        const float* xm = xmask + (size_t)bp * 16;
        int k = 0;
#pragma unroll
        for (int i = 0; i < 16; ++i) k = (xm[i] > 0.5f) ? i : k;
        const float4* src = (const float4*)(wg + (size_t)k * 4096);
        float4*       dst = (float4*)(wout + (size_t)bp * 4096);
#pragma unroll
        for (int c = 0; c < 4; ++c)
            dst[c * 256 + tid] = src[c * 256 + tid];
        return;
    }

    const int zb = blockIdx.x - 8192;
    const int b  = zb >> 2;
    const int iq = zb & 3;
    const int wv = tid >> 6;
    const int ln = tid & 63;

    if (tid < 128) {
        const float* xm = xmask + ((size_t)b * 128 + tid) * 16;
        int k = 0;
#pragma unroll
        for (int i = 0; i < 16; ++i) k = (xm[i] > 0.5f) ? i : k;
        idx[tid] = k;
    }
#pragma unroll
    for (int c = 0; c < 16; ++c)
        ((float*)sw)[c * 256 + tid] = 0.f;
    __syncthreads();

    // wave wv owns p in [wv*32, wv*32+32); lane = j; x read direct (L2-hot).
    const float* xb = x + (size_t)b * 8192;
    for (int p = wv * 32; p < wv * 32 + 32; ++p) {
        int k = idx[p];
        sw[wv][k][ln] += xb[p * 64 + ln];
    }
    __syncthreads();

    for (int e = tid; e < 1024; e += 256) {
        int k2 = e >> 6, j = e & 63;
        sw[0][k2][j] = sw[0][k2][j] + sw[1][k2][j] + sw[2][k2][j] + sw[3][k2][j];
    }
    __syncthreads();

    {
        const int k  = tid >> 4;
        const int il = tid & 15;
        const int i  = iq * 16 + il;
        float a = 0.f;
        const float4* Er = (const float4*)(E + (size_t)k * 4096 + i * 64);
        const float4* sr = (const float4*)(&sw[0][k][0]);
#pragma unroll
        for (int j4 = 0; j4 < 16; ++j4) {
            float4 e4 = Er[j4];
            float4 s4 = sr[j4];
            a = fmaf(e4.x, s4.x, a);
            a = fmaf(e4.y, s4.y, a);
            a = fmaf(e4.z, s4.z, a);
            a = fmaf(e4.w, s4.w, a);
        }
        zr[k][il] = a;
    }
    __syncthreads();
    if (tid < 16) {
        float s = 0.f;
#pragma unroll
        for (int k = 0; k < 16; ++k) s += zr[k][tid];
        zout[b * 64 + iq * 16 + tid] = s;
    }
}

extern "C" void kernel_launch(void* const* d_in, const int* in_sizes, int n_in,
                              void* d_out, int out_size, void* d_ws, size_t ws_size,
                              hipStream_t stream) {
    const float* x     = (const float*)d_in[0];   // [64,64,128]
    const float* xmask = (const float*)d_in[1];   // [64,128,16]
    const float* W     = (const float*)d_in[2];   // [16,4096]
    const float* G     = (const float*)d_in[3];   // [4096,4096]

    float* zout = (float*)d_out;                  // [64,64]
    float* wout = (float*)d_out + 4096;           // [64,128,4096]

    float*    wg  = (float*)d_ws;                 // 64K f32
    float*    E   = wg + 65536;                   // 64K f32
    unsigned* cnt = (unsigned*)(E + 65536);       // 64 counters

    // partials live in the (dead-until-overwritten) w output region: 4 MB
    float* part = wout;                           // 16 tc * 16 k * 4096 m f32

    // d_ws is poisoned 0xAA before timing; counters must start at 0 each call.
    hipMemsetAsync(cnt, 0, 64 * sizeof(unsigned), stream);

    k_gemm<<<1024, 256, 0, stream>>>(W, G, part, wg, E, cnt);
    k_wz  <<<8448, 256, 0, stream>>>(x, xmask, wg, E, wout, zout);
}

// Round 6
// 52.604 us; speedup vs baseline: 3.5260x; 3.5260x over previous
//
#include <hip/hip_runtime.h>
#include <hip/hip_bf16.h>

// B=64, N=64, P=128, K=16, M=N*N=4096, T=4096
// Outputs: Z [64,64] then w [64,128,4096], concatenated f32.
//
// Pipeline (3 kernels, no cross-block sync — R5 lesson: agent-scope fences
// at grid width cost ~130us in per-XCD L2 writebacks; a launch gap is 2us):
//   k_gemm   : part[tc][k][m] = sum_{t in 256-chunk} W[k][t]^2 * G[t][m]
//              (W^2 staged in LDS, reduction staging aliased onto it: 32 KB
//               -> 5 blocks/CU -> all 1024 blocks co-resident)
//   k_reduce : wg = sum_tc part ; E = exp(-wg)
//   k_wz     : blocks 0..8191    -> w[b,p,:] = wg[idx(b,p)][:]
//              blocks 8192..8447 -> Z[b][i] = sum_k E[k][i,:] . s[b,k,:]

// ---------------------------------------------------------------------------
__global__ __launch_bounds__(256) void k_gemm(const float* __restrict__ W,
                                              const float* __restrict__ G,
                                              float* __restrict__ part) {
    __shared__ float buf[8192];        // 32 KB: w2 [16][256], then red staging
    const int tc  = blockIdx.x & 15;   // t-chunk (256 t each)
    const int mg  = blockIdx.x >> 4;   // m-slice (64 floats = 16 float4 each)
    const int tid = threadIdx.x;
    const int tt  = tid >> 4;          // 0..15 t-sublane
    const int col = tid & 15;          // 0..15 float4 within m-slice
    const int t0  = tc * 256;

    // stage W^2 for this t-chunk (coalesced per k)
#pragma unroll
    for (int k = 0; k < 16; ++k) {
        float v = W[k * 4096 + t0 + tid];
        buf[k * 256 + tid] = v * v;
    }
    __syncthreads();

    const float4* G4 = (const float4*)G;
    const int mq = mg * 16 + col;      // float4 column (0..1023)

    float4 acc[16];
#pragma unroll
    for (int k = 0; k < 16; ++k) acc[k] = make_float4(0.f, 0.f, 0.f, 0.f);

#pragma unroll 8
    for (int i = 0; i < 16; ++i) {
        const int tl = tt * 16 + i;
        const float4 g4 = G4[(size_t)(t0 + tl) * 1024 + mq];
#pragma unroll
        for (int k = 0; k < 16; ++k) {
            const float s = buf[k * 256 + tl];
            acc[k].x = fmaf(s, g4.x, acc[k].x);
            acc[k].y = fmaf(s, g4.y, acc[k].y);
            acc[k].z = fmaf(s, g4.z, acc[k].z);
            acc[k].w = fmaf(s, g4.w, acc[k].w);
        }
    }
    __syncthreads();                   // w2 dead; reuse buf as red staging

    // in-block reduction over tt: 2 rounds of 8 k (red aliases buf, 32 KB)
    float4* red = (float4*)buf;
    float4* p4  = (float4*)part;
#pragma unroll
    for (int r = 0; r < 2; ++r) {
#pragma unroll
        for (int ks = 0; ks < 8; ++ks)
            red[ks * 256 + tid] = acc[r * 8 + ks];
        __syncthreads();
        if (tid < 128) {
            const int ks = tid >> 4;   // 0..7
            const int c2 = tid & 15;   // 0..15
            float4 s = make_float4(0.f, 0.f, 0.f, 0.f);
#pragma unroll
            for (int t2 = 0; t2 < 16; ++t2) {
                float4 v = red[ks * 256 + t2 * 16 + c2];
                s.x += v.x; s.y += v.y; s.z += v.z; s.w += v.w;
            }
            const int k = r * 8 + ks;
            p4[(size_t)tc * 16384 + (size_t)k * 1024 + mg * 16 + c2] = s;
        }
        __syncthreads();
    }
}

// ---------------------------------------------------------------------------
// grid 64 x 256: thread owns one float4 of wg/E, sums 16 tc partials.
__global__ __launch_bounds__(256) void k_reduce(const float* __restrict__ part,
                                                float* __restrict__ wg,
                                                float* __restrict__ E) {
    const int q = blockIdx.x * 256 + threadIdx.x;    // f4 id 0..16383
    const float4* p4 = (const float4*)part;
    float4 s = make_float4(0.f, 0.f, 0.f, 0.f);
#pragma unroll
    for (int tc = 0; tc < 16; ++tc) {
        float4 v = p4[(size_t)tc * 16384 + q];
        s.x += v.x; s.y += v.y; s.z += v.z; s.w += v.w;
    }
    ((float4*)wg)[q] = s;
    ((float4*)E)[q] = make_float4(expf(-s.x), expf(-s.y), expf(-s.z), expf(-s.w));
}

// ---------------------------------------------------------------------------
// blocks 0..8191: w gather.  blocks 8192..8447: Z (b = zb>>2, iq = zb&3).
__global__ __launch_bounds__(256) void k_wz(const float* __restrict__ x,
                                            const float* __restrict__ xmask,
                                            const float* __restrict__ wg,
                                            const float* __restrict__ E,
                                            float* __restrict__ wout,
                                            float* __restrict__ zout) {
    __shared__ float sw[4][16][64];   // 16 KB (z only)
    __shared__ int   idx[128];
    __shared__ float zr[16][16];
    const int tid = threadIdx.x;

    if (blockIdx.x < 8192) {
        const int bp = blockIdx.x;
        const float* xm = xmask + (size_t)bp * 16;
        int k = 0;
#pragma unroll
        for (int i = 0; i < 16; ++i) k = (xm[i] > 0.5f) ? i : k;
        const float4* src = (const float4*)(wg + (size_t)k * 4096);
        float4*       dst = (float4*)(wout + (size_t)bp * 4096);
#pragma unroll
        for (int c = 0; c < 4; ++c)
            dst[c * 256 + tid] = src[c * 256 + tid];
        return;
    }

    const int zb = blockIdx.x - 8192;
    const int b  = zb >> 2;
    const int iq = zb & 3;
    const int wv = tid >> 6;
    const int ln = tid & 63;

    if (tid < 128) {
        const float* xm = xmask + ((size_t)b * 128 + tid) * 16;
        int k = 0;
#pragma unroll
        for (int i = 0; i < 16; ++i) k = (xm[i] > 0.5f) ? i : k;
        idx[tid] = k;
    }
#pragma unroll
    for (int c = 0; c < 16; ++c)
        ((float*)sw)[c * 256 + tid] = 0.f;
    __syncthreads();

    // wave wv owns p in [wv*32, wv*32+32); lane = j; x read direct (L2-hot).
    const float* xb = x + (size_t)b * 8192;
    for (int p = wv * 32; p < wv * 32 + 32; ++p) {
        int k = idx[p];
        sw[wv][k][ln] += xb[p * 64 + ln];
    }
    __syncthreads();

    for (int e = tid; e < 1024; e += 256) {
        int k2 = e >> 6, j = e & 63;
        sw[0][k2][j] = sw[0][k2][j] + sw[1][k2][j] + sw[2][k2][j] + sw[3][k2][j];
    }
    __syncthreads();

    {
        const int k  = tid >> 4;
        const int il = tid & 15;
        const int i  = iq * 16 + il;
        float a = 0.f;
        const float4* Er = (const float4*)(E + (size_t)k * 4096 + i * 64);
        const float4* sr = (const float4*)(&sw[0][k][0]);
#pragma unroll
        for (int j4 = 0; j4 < 16; ++j4) {
            float4 e4 = Er[j4];
            float4 s4 = sr[j4];
            a = fmaf(e4.x, s4.x, a);
            a = fmaf(e4.y, s4.y, a);
            a = fmaf(e4.z, s4.z, a);
            a = fmaf(e4.w, s4.w, a);
        }
        zr[k][il] = a;
    }
    __syncthreads();
    if (tid < 16) {
        float s = 0.f;
#pragma unroll
        for (int k = 0; k < 16; ++k) s += zr[k][tid];
        zout[b * 64 + iq * 16 + tid] = s;
    }
}

extern "C" void kernel_launch(void* const* d_in, const int* in_sizes, int n_in,
                              void* d_out, int out_size, void* d_ws, size_t ws_size,
                              hipStream_t stream) {
    const float* x     = (const float*)d_in[0];   // [64,64,128]
    const float* xmask = (const float*)d_in[1];   // [64,128,16]
    const float* W     = (const float*)d_in[2];   // [16,4096]
    const float* G     = (const float*)d_in[3];   // [4096,4096]

    float* zout = (float*)d_out;                  // [64,64]
    float* wout = (float*)d_out + 4096;           // [64,128,4096]

    float* wg = (float*)d_ws;                     // 64K f32
    float* E  = wg + 65536;                       // 64K f32

    // partials live in the (dead-until-overwritten) w output region: 4 MB
    float* part = wout;                           // 16 tc * 16 k * 4096 m f32

    k_gemm  <<<1024, 256, 0, stream>>>(W, G, part);
    k_reduce<<<64,   256, 0, stream>>>(part, wg, E);
    k_wz    <<<8448, 256, 0, stream>>>(x, xmask, wg, E, wout, zout);
}

// Round 7
// 50.618 us; speedup vs baseline: 3.6644x; 1.0392x over previous
//
#include <hip/hip_runtime.h>
#include <hip/hip_bf16.h>

// B=64, N=64, P=128, K=16, M=N*N=4096, T=4096
// Outputs: Z [64,64] then w [64,128,4096], concatenated f32.
//
// Pipeline (3 kernels, no cross-block sync — R5 lesson: device-scope fences
// at grid width cost ~130us in per-XCD L2 writebacks):
//   k_gemm   : part[tc][k][m] = sum_{t in 256-chunk} W[k][t]^2 * G[t][m]
//              G staged via global_load_lds double-buffer (R6 lesson: VGPR-held
//              loads cap in-flight bytes at ~2KB/CU -> latency-bound; DMA holds
//              no VGPRs -> 16KB/CU in flight).
//   k_reduce : wg = sum_tc part ; E = exp(-wg)
//   k_wz     : blocks 0..8191    -> w[b,p,:] = wg[idx(b,p)][:]
//              blocks 8192..8447 -> Z[b][i] = sum_k E[k][i,:] . s[b,k,:]

__device__ __forceinline__ void dma16(const void* g, void* l) {
    __builtin_amdgcn_global_load_lds(
        (const __attribute__((address_space(1))) void*)g,
        (__attribute__((address_space(3))) void*)l, 16, 0, 0);
}

// ---------------------------------------------------------------------------
__global__ __launch_bounds__(256) void k_gemm(const float* __restrict__ W,
                                              const float* __restrict__ G,
                                              float* __restrict__ part) {
    __shared__ float buf[8192];               // 32 KB
    float4* w2t4 = (float4*)buf;              // w2t[256][16] floats = 16 KB
    float4* stg  = (float4*)(buf + 4096);     // 2 stage buffers x 256 f4 = 8 KB

    const int tc  = blockIdx.x & 15;          // t-chunk (256 t each)
    const int mg  = blockIdx.x >> 4;          // m-slice (64 floats)
    const int tid = threadIdx.x;
    const int wv  = tid >> 6;
    const int ln  = tid & 63;
    const int tt  = tid >> 4;                 // 0..15 t-sublane
    const int t0  = tc * 256;

    // stage W^2 TRANSPOSED: w2t[tl][k] (so per-stage weight read = 4x b128)
    {
        float v[16];
#pragma unroll
        for (int k = 0; k < 16; ++k) {
            float w = W[k * 4096 + t0 + tid];
            v[k] = w * w;
        }
#pragma unroll
        for (int q = 0; q < 4; ++q)
            w2t4[tid * 4 + q] = make_float4(v[4*q], v[4*q+1], v[4*q+2], v[4*q+3]);
    }

    const float4* G4 = (const float4*)G;
    // DMA mapping: lane fi = wv*64+ln covers (t_local = fi>>4, mcol = fi&15);
    // LDS dest is wave-uniform base, lane auto-writes at +ln*16B (matches fi).
    const int fi  = wv * 64 + ln;
    const int tl_ = fi >> 4;
    const int mc_ = fi & 15;

    dma16(&G4[(size_t)(t0 + tl_) * 1024 + mg * 16 + mc_], &stg[wv * 64]);
    __syncthreads();                          // drains w2t writes + stage-0 DMA

    float4 acc[16];
#pragma unroll
    for (int k = 0; k < 16; ++k) acc[k] = make_float4(0.f, 0.f, 0.f, 0.f);

    for (int s = 0; s < 16; ++s) {
        if (s < 15)                           // prefetch next tile (other buffer)
            dma16(&G4[(size_t)(t0 + (s + 1) * 16 + tl_) * 1024 + mg * 16 + mc_],
                  &stg[((s + 1) & 1) * 256 + wv * 64]);

        const float4 g4 = stg[(s & 1) * 256 + tid];     // (t=s*16+tt, col) = slot tid
        const float4* wr = &w2t4[(s * 16 + tt) * 4];
#pragma unroll
        for (int q = 0; q < 4; ++q) {
            const float4 wq = wr[q];
            const float* wf = (const float*)&wq;
#pragma unroll
            for (int c = 0; c < 4; ++c) {
                const float sc = wf[c];
                acc[q*4+c].x = fmaf(sc, g4.x, acc[q*4+c].x);
                acc[q*4+c].y = fmaf(sc, g4.y, acc[q*4+c].y);
                acc[q*4+c].z = fmaf(sc, g4.z, acc[q*4+c].z);
                acc[q*4+c].w = fmaf(sc, g4.w, acc[q*4+c].w);
            }
        }
        __syncthreads();   // vmcnt(0) drain: next tile landed; buffer reuse safe
    }

    // in-block reduction over tt: 2 rounds of 8 k (red aliases buf, 32 KB)
    float4* red = (float4*)buf;
    float4* p4  = (float4*)part;
    const int col = tid & 15;
    (void)col;
#pragma unroll
    for (int r = 0; r < 2; ++r) {
#pragma unroll
        for (int ks = 0; ks < 8; ++ks)
            red[ks * 256 + tid] = acc[r * 8 + ks];
        __syncthreads();
        if (tid < 128) {
            const int ks = tid >> 4;   // 0..7
            const int c2 = tid & 15;   // 0..15
            float4 s = make_float4(0.f, 0.f, 0.f, 0.f);
#pragma unroll
            for (int t2 = 0; t2 < 16; ++t2) {
                float4 v = red[ks * 256 + t2 * 16 + c2];
                s.x += v.x; s.y += v.y; s.z += v.z; s.w += v.w;
            }
            const int k = r * 8 + ks;
            p4[(size_t)tc * 16384 + (size_t)k * 1024 + mg * 16 + c2] = s;
        }
        __syncthreads();
    }
}

// ---------------------------------------------------------------------------
// grid 64 x 256: thread owns one float4 of wg/E, sums 16 tc partials.
__global__ __launch_bounds__(256) void k_reduce(const float* __restrict__ part,
                                                float* __restrict__ wg,
                                                float* __restrict__ E) {
    const int q = blockIdx.x * 256 + threadIdx.x;    // f4 id 0..16383
    const float4* p4 = (const float4*)part;
    float4 s = make_float4(0.f, 0.f, 0.f, 0.f);
#pragma unroll
    for (int tc = 0; tc < 16; ++tc) {
        float4 v = p4[(size_t)tc * 16384 + q];
        s.x += v.x; s.y += v.y; s.z += v.z; s.w += v.w;
    }
    ((float4*)wg)[q] = s;
    ((float4*)E)[q] = make_float4(expf(-s.x), expf(-s.y), expf(-s.z), expf(-s.w));
}

// ---------------------------------------------------------------------------
// blocks 0..8191: w gather.  blocks 8192..8447: Z (b = zb>>2, iq = zb&3).
__global__ __launch_bounds__(256) void k_wz(const float* __restrict__ x,
                                            const float* __restrict__ xmask,
                                            const float* __restrict__ wg,
                                            const float* __restrict__ E,
                                            float* __restrict__ wout,
                                            float* __restrict__ zout) {
    __shared__ float sw[4][16][64];   // 16 KB (z only)
    __shared__ int   idx[128];
    __shared__ float zr[16][16];
    const int tid = threadIdx.x;

    if (blockIdx.x < 8192) {
        const int bp = blockIdx.x;
        const float* xm = xmask + (size_t)bp * 16;
        int k = 0;
#pragma unroll
        for (int i = 0; i < 16; ++i) k = (xm[i] > 0.5f) ? i : k;
        const float4* src = (const float4*)(wg + (size_t)k * 4096);
        float4*       dst = (float4*)(wout + (size_t)bp * 4096);
#pragma unroll
        for (int c = 0; c < 4; ++c)
            dst[c * 256 + tid] = src[c * 256 + tid];
        return;
    }

    const int zb = blockIdx.x - 8192;
    const int b  = zb >> 2;
    const int iq = zb & 3;
    const int wv = tid >> 6;
    const int ln = tid & 63;

    if (tid < 128) {
        const float* xm = xmask + ((size_t)b * 128 + tid) * 16;
        int k = 0;
#pragma unroll
        for (int i = 0; i < 16; ++i) k = (xm[i] > 0.5f) ? i : k;
        idx[tid] = k;
    }
#pragma unroll
    for (int c = 0; c < 16; ++c)
        ((float*)sw)[c * 256 + tid] = 0.f;
    __syncthreads();

    // wave wv owns p in [wv*32, wv*32+32); lane = j; x read direct (L2-hot).
    const float* xb = x + (size_t)b * 8192;
    for (int p = wv * 32; p < wv * 32 + 32; ++p) {
        int k = idx[p];
        sw[wv][k][ln] += xb[p * 64 + ln];
    }
    __syncthreads();

    for (int e = tid; e < 1024; e += 256) {
        int k2 = e >> 6, j = e & 63;
        sw[0][k2][j] = sw[0][k2][j] + sw[1][k2][j] + sw[2][k2][j] + sw[3][k2][j];
    }
    __syncthreads();

    {
        const int k  = tid >> 4;
        const int il = tid & 15;
        const int i  = iq * 16 + il;
        float a = 0.f;
        const float4* Er = (const float4*)(E + (size_t)k * 4096 + i * 64);
        const float4* sr = (const float4*)(&sw[0][k][0]);
#pragma unroll
        for (int j4 = 0; j4 < 16; ++j4) {
            float4 e4 = Er[j4];
            float4 s4 = sr[j4];
            a = fmaf(e4.x, s4.x, a);
            a = fmaf(e4.y, s4.y, a);
            a = fmaf(e4.z, s4.z, a);
            a = fmaf(e4.w, s4.w, a);
        }
        zr[k][il] = a;
    }
    __syncthreads();
    if (tid < 16) {
        float s = 0.f;
#pragma unroll
        for (int k = 0; k < 16; ++k) s += zr[k][tid];
        zout[b * 64 + iq * 16 + tid] = s;
    }
}

extern "C" void kernel_launch(void* const* d_in, const int* in_sizes, int n_in,
                              void* d_out, int out_size, void* d_ws, size_t ws_size,
                              hipStream_t stream) {
    const float* x     = (const float*)d_in[0];   // [64,64,128]
    const float* xmask = (const float*)d_in[1];   // [64,128,16]
    const float* W     = (const float*)d_in[2];   // [16,4096]
    const float* G     = (const float*)d_in[3];   // [4096,4096]

    float* zout = (float*)d_out;                  // [64,64]
    float* wout = (float*)d_out + 4096;           // [64,128,4096]

    float* wg = (float*)d_ws;                     // 64K f32
    float* E  = wg + 65536;                       // 64K f32

    // partials live in the (dead-until-overwritten) w output region: 4 MB
    float* part = wout;                           // 16 tc * 16 k * 4096 m f32

    k_gemm  <<<1024, 256, 0, stream>>>(W, G, part);
    k_reduce<<<64,   256, 0, stream>>>(part, wg, E);
    k_wz    <<<8448, 256, 0, stream>>>(x, xmask, wg, E, wout, zout);
}